// Round 5
// baseline (811.433 us; speedup 1.0000x reference)
//
#include <hip/hip_runtime.h>
#include <math.h>

#define NB 16
#define NN 2048
#define ND 256
#define BNtot (NB*NN)
#define HH 33554432u   // 2^25 = half of 16*2048*2048 (threefry counter split)

__device__ __forceinline__ unsigned rotl(unsigned v, int r){
  return __builtin_amdgcn_alignbit(v, v, 32-r);   // single v_alignbit_b32
}
__device__ __forceinline__ unsigned umaxu(unsigned a, unsigned b){ return a > b ? a : b; }
__device__ __forceinline__ unsigned uminu(unsigned a, unsigned b){ return a < b ? a : b; }

// ---------------- threefry2x32, bit-exact vs jax.random.key(42) ----------------
__device__ __forceinline__ float gumbelv(unsigned b, unsigned n, unsigned m){
  unsigned f = (b<<22) | (n<<11) | m;
  unsigned x0 = (b < 8u) ? f : (f - HH);
  unsigned x1 = x0 + HH;
  const unsigned ks0=0u, ks1=42u, ks2=0u^42u^0x1BD11BDAu;
  unsigned v0 = x0 + ks0;
  unsigned v1 = x1 + ks1;
#define TFR(r) { v0 += v1; v1 = rotl(v1,(r)); v1 ^= v0; }
  TFR(13) TFR(15) TFR(26) TFR(6)
  v0 += ks1; v1 += ks2 + 1u;
  TFR(17) TFR(29) TFR(16) TFR(24)
  v0 += ks2; v1 += ks0 + 2u;
  TFR(13) TFR(15) TFR(26) TFR(6)
  v0 += ks0; v1 += ks1 + 3u;
  TFR(17) TFR(29) TFR(16) TFR(24)
  v0 += ks1; v1 += ks2 + 4u;
  TFR(13) TFR(15) TFR(26) TFR(6)
  v0 += ks2; v1 += ks0 + 5u;
#undef TFR
  unsigned bits = (b < 8u) ? v0 : v1;
  float fl = __uint_as_float((bits>>9) | 0x3F800000u) - 1.0f;
  float u = fmaxf(1e-10f, fl + 1e-10f);
  return -logf(-logf(u));
}

// g from 23-bit key, exactly as JAX: fl = as_float(key|0x3f800000)-1
__device__ __forceinline__ float gfromkey(unsigned key){
  float fl = __uint_as_float(key | 0x3F800000u) - 1.0f;
  float u = fmaxf(1e-10f, fl + 1e-10f);
  return -logf(-logf(u));
}

// ---------------- gumbel scan state ----------------
// Task t scans 64 of a 128-chunk's values (half = t&1); lane-pairs merge via
// shfl_xor(1). packed cand = (key bits 31..9) | vk, vk = 7-bit descending counter:
// integer max = max gumbel, ties -> smallest n. 16 chunks x top-2 = 32 candidates
// per (b,m) column, stored TRANSPOSED: pck[(b*NN+m)*32 + nq*2 + rank] so the
// consumer's 32-candidate read is one coalesced 128B wave load.
struct GumState {
  unsigned x0, vk, a1, a2, c1, c2;
  int t;
};

__device__ __forceinline__ void gum_init(GumState& g, int t){
  g.t = t;
  int half = t & 1;
  int m    = (t >> 1) & 2047;
  int bl   = (t >> 12) & 7;
  int nq   = t >> 15;                        // 0..15, chunk of 128
  int nstart = (nq << 7) + (half << 6);      // this thread's 64 values
  g.x0 = ((unsigned)bl << 22) | ((unsigned)nstart << 11) | (unsigned)m;
  g.a1 = g.a2 = g.c1 = g.c2 = 0;
  g.vk = (unsigned)(127 - (half<<6));        // descending; n = chunkbase + 127 - vk
}

__device__ __forceinline__ void gum_iter(GumState& g, const int cnt){
  const unsigned KS2 = 42u ^ 0x1BD11BDAu;
  unsigned x0=g.x0, vk=g.vk, a1=g.a1, a2=g.a2, c1=g.c1, c2=g.c2;
#define TFR(r)       { v0 += v1; v1 = rotl(v1,(r)); v1 ^= v0; }
#define TFRI(r, inj) { v0 += v1 + (inj); v1 = rotl(v1,(r)); v1 ^= v0; }
  #pragma unroll 4
  for (int j = 0; j < cnt; ++j){
    unsigned v0 = x0;
    unsigned v1 = x0 + (HH + 42u);
    TFR(13) TFR(15) TFR(26) TFR(6)
    v1 += KS2 + 1u;
    TFRI(17, 42u) TFR(29) TFR(16) TFR(24)
    v1 += 2u;
    TFRI(13, KS2) TFR(15) TFR(26) TFR(6)
    v1 += 42u + 3u;
    TFR(17) TFR(29) TFR(16) TFR(24)     /* v0 += 0 before this group */
    v1 += KS2 + 4u;
    TFRI(13, 42u) TFR(15) TFR(26) TFR(6)
    v0 += KS2; v1 += 5u;
    unsigned pa = (v0 & 0xFFFFFE00u) | vk;   // v_and_or_b32
    unsigned pb = (v1 & 0xFFFFFE00u) | vk;
    unsigned ta = uminu(pa, a1);
    a1 = umaxu(pa, a1);
    a2 = umaxu(ta, a2);
    unsigned tc = uminu(pb, c1);
    c1 = umaxu(pb, c1);
    c2 = umaxu(tc, c2);
    x0 += 2048u;
    vk -= 1u;
  }
#undef TFR
#undef TFRI
  g.x0=x0; g.vk=vk; g.a1=a1; g.a2=a2; g.c1=c1; g.c2=c2;
}

__device__ __forceinline__ void gum_finish(const GumState& g, unsigned* __restrict__ pck){
  int half = g.t & 1;
  int m    = (g.t >> 1) & 2047;
  int bl   = (g.t >> 12) & 7;
  int nq   = g.t >> 15;
  // merge with partner lane (other half of the chunk)
  unsigned p1 = __shfl_xor((int)g.a1, 1), p2 = __shfl_xor((int)g.a2, 1);
  unsigned q1 = __shfl_xor((int)g.c1, 1), q2 = __shfl_xor((int)g.c2, 1);
  unsigned A1 = umaxu(g.a1, p1);
  unsigned A2 = umaxu(uminu(g.a1, p1), umaxu(g.a2, p2));
  unsigned C1 = umaxu(g.c1, q1);
  unsigned C2 = umaxu(uminu(g.c1, q1), umaxu(g.c2, q2));
  if (half == 0){
    uint2 ua; ua.x = A1; ua.y = A2;
    uint2 uc; uc.x = C1; uc.y = C2;
    *(uint2*)(&pck[((size_t)bl*NN + m)*32 + (nq<<1)])     = ua;   // batch bl
    *(uint2*)(&pck[((size_t)(bl+8)*NN + m)*32 + (nq<<1)]) = uc;   // batch bl+8
  }
}

// norms for 4 rows held in registers: wave shuffle-reduce (same order as knorms)
__device__ __forceinline__ void norm_rows(const float4* v, int wid, int lane,
                                          float* __restrict__ nrm){
  #pragma unroll
  for (int i=0;i<4;i++){
    float s = v[i].x*v[i].x + v[i].y*v[i].y + v[i].z*v[i].z + v[i].w*v[i].w;
    for (int o=32;o;o>>=1) s += __shfl_down(s,o);
    if (lane==0) nrm[wid*4 + i] = sqrtf(s);
  }
}

// ---------------- row norms (last-resort tier) ----------------
__global__ void knorms(const float* __restrict__ LLF, const float* __restrict__ HLF,
                       float* __restrict__ nl, float* __restrict__ nh){
  int row = blockIdx.x;
  int wave = threadIdx.x >> 6;
  int lane = threadIdx.x & 63;
  const float* src = wave ? HLF : LLF;
  float4 v = ((const float4*)(src + (size_t)row*ND))[lane];
  float s = v.x*v.x + v.y*v.y + v.z*v.z + v.w*v.w;
  for (int o=32;o;o>>=1) s += __shfl_down(s,o);
  if (lane==0) (wave? nh: nl)[row] = sqrtf(s);
}

// ---------------- fused kernel 1: norms + full gumbel (thread-granular, R3-proven) ----------------
// 2048 blocks x 256 thr = 8192 waves = 32 waves/CU: whole grid resident from t=0,
// retires together. Each wave norms 4 LLF + 4 HLF rows; loads issued ahead of
// 32-iter gumbel chunks which hide the HBM latency. No bf16 pack anymore (GEMM
// eliminated) -> writes are just nl/nh + pck (~4.3 MB).
__launch_bounds__(256, 8)
__global__ void kfuse1(const float* __restrict__ LLF, const float* __restrict__ HLF,
                       float* __restrict__ nl, float* __restrict__ nh,
                       unsigned* __restrict__ pck){
  int t = blockIdx.x*256 + (int)threadIdx.x;
  int wid = t >> 6;
  int lane = t & 63;
  GumState g; gum_init(g, t);
  float4 va[4];
  #pragma unroll
  for (int i=0;i<4;i++)
    va[i] = ((const float4*)(LLF + (size_t)(wid*4+i)*ND))[lane];
  gum_iter(g, 32);
  norm_rows(va, wid, lane, nl);
  float4 vb[4];
  #pragma unroll
  for (int i=0;i<4;i++)
    vb[i] = ((const float4*)(HLF + (size_t)(wid*4+i)*ND))[lane];
  gum_iter(g, 32);
  norm_rows(vb, wid, lane, nh);
  gum_finish(g, pck);
}

// ---------------- resolve: interval-argmax over 32 packed candidates ----------------
// Math: sim = cos/16 in [-1/16,1/16] exactly, so e_n = exp(sim-1/16) in [0.8825,1]
// and invS = 1/sum(e_n) in [1/2048, e^0.125/2048]. Column prob spread <=
// IHI*0.1175 = 6.5e-5 < the 8e-5 candidate window (same bound the old GEMM path
// relied on). q_i(invS) = e_i*invS + g_i is linear in invS, so if the argmax at
// both interval endpoints agrees, it is the argmax for the true invS (pairwise
// dominance). Fast path (one candidate in window, ~(1-8e-5) of columns): no dots,
// no softmax at all. Interval margins +-0.15% cover fp32 summation error of the
// exact fallback.
#define ILO 4.882e-4f
#define IHI 5.534e-4f
__launch_bounds__(256)
__global__ void kresolve(const float* __restrict__ LLF, const float* __restrict__ HLF,
                         const float* __restrict__ nl, const float* __restrict__ nh,
                         const unsigned* __restrict__ pck,
                         int* __restrict__ idx){
  int w    = threadIdx.x >> 6;               // wave within block
  int lane = threadIdx.x & 63;
  int g = blockIdx.x*4 + w;                  // b*NN+m
  int b = g >> 11;
  float pv = -INFINITY; int pn = 0;
  if (lane < 32){                            // candidate c = lane: nq = c>>1, rank = c&1
    unsigned pk = pck[(size_t)g*32 + lane];  // coalesced 128B per wave
    pv = gfromkey(pk >> 9);
    pn = ((lane >> 1) << 7) + 127 - (int)(pk & 127u);
  }
  float gmax = pv;
  for (int o=32;o;o>>=1) gmax = fmaxf(gmax, __shfl_down(gmax,o));
  gmax = __shfl(gmax, 0);
  unsigned long long mask = __ballot(pv >= gmax - 8e-5f) & 0xFFFFFFFFull;
  if (__popcll(mask) == 1){
    int src = __builtin_ctzll(mask);
    int n = __shfl(pn, src);
    if (lane==0) idx[g] = n;
    return;
  }
  // ---- multi-candidate (expected ~3 columns of 32768): fp32 dots + endpoint test
  float4 h = ((const float4*)(HLF + (size_t)g*ND))[lane];
  float nhg = nh[g];
  float bestLo = -INFINITY, bestHi = -INFINITY;
  int nLo = 1<<30, nHi = 1<<30;
  unsigned long long mm = mask;
  while (mm){
    int src = __builtin_ctzll(mm); mm &= mm-1;
    int   n  = __shfl(pn, src);
    float gv = __shfl(pv, src);
    float4 a = ((const float4*)(LLF + ((size_t)b*NN + n)*ND))[lane];
    float d = a.x*h.x + a.y*h.y + a.z*h.z + a.w*h.w;
    for (int o=32;o;o>>=1) d += __shfl_down(d,o);
    d = __shfl(d, 0);
    float sim = (d / fmaxf(nl[b*NN+n]*nhg, 1e-8f)) * 0.0625f;
    float e = expf(sim - 0.0625f);
    float qlo = e*ILO + gv;
    float qhi = e*IHI + gv;
    if (qlo > bestLo || (qlo == bestLo && n < nLo)){ bestLo = qlo; nLo = n; }
    if (qhi > bestHi || (qhi == bestHi && n < nHi)){ bestHi = qhi; nHi = n; }
  }
  if (nLo == nHi){
    if (lane==0) idx[g] = nLo;
    return;
  }
  // ---- exact fallback (P ~ 1e-5 per run): full column softmax denominator
  float S = 0.0f;
  for (int n2 = 0; n2 < NN; ++n2){
    float4 a = ((const float4*)(LLF + ((size_t)b*NN + n2)*ND))[lane];
    float d = a.x*h.x + a.y*h.y + a.z*h.z + a.w*h.w;
    for (int o=32;o;o>>=1) d += __shfl_down(d,o);
    d = __shfl(d, 0);
    float sim = (d / fmaxf(nl[b*NN+n2]*nhg, 1e-8f)) * 0.0625f;
    S += expf(sim - 0.0625f);
  }
  float invS = 1.0f / S;
  float bestQ = -INFINITY; int bestN = 1<<30;
  mm = mask;
  while (mm){
    int src = __builtin_ctzll(mm); mm &= mm-1;
    int   n  = __shfl(pn, src);
    float gv = __shfl(pv, src);
    float4 a = ((const float4*)(LLF + ((size_t)b*NN + n)*ND))[lane];
    float d = a.x*h.x + a.y*h.y + a.z*h.z + a.w*h.w;
    for (int o=32;o;o>>=1) d += __shfl_down(d,o);
    d = __shfl(d, 0);
    float sim = (d / fmaxf(nl[b*NN+n]*nhg, 1e-8f)) * 0.0625f;
    float q = expf(sim - 0.0625f)*invS + gv;
    if (q > bestQ || (q == bestQ && n < bestN)){ bestQ = q; bestN = n; }
  }
  if (lane==0) idx[g] = bestN;
}

// ---------------- last-resort fallback (tiny ws) ----------------
__launch_bounds__(256)
__global__ void kstats(const float* __restrict__ A, const float* __restrict__ Bm,
                       const float* __restrict__ nl, const float* __restrict__ nh,
                       float* __restrict__ Mout, float* __restrict__ Sinv){
  __shared__ float As[64][33];
  __shared__ float Bs[64][33];
  __shared__ float Cs[64][65];
  const int b  = blockIdx.x >> 5;
  const int m0 = (blockIdx.x & 31) << 6;
  const float* Ab = A  + (size_t)b*NN*ND;
  const float* Bb = Bm + (size_t)b*NN*ND;
  const int tid = threadIdx.x;
  const int tx = tid & 15, ty = tid >> 4;
  float nhv[4];
  #pragma unroll
  for (int j=0;j<4;j++) nhv[j] = nh[b*NN + m0 + tx*4 + j];
  float Mr = -INFINITY, Sr = 0.0f;
  for (int nt=0; nt<NN; nt+=64){
    float acc[4][4] = {{0.f,0.f,0.f,0.f},{0.f,0.f,0.f,0.f},{0.f,0.f,0.f,0.f},{0.f,0.f,0.f,0.f}};
    for (int kc=0; kc<ND; kc+=32){
      __syncthreads();
      #pragma unroll
      for (int s=0;s<2;s++){
        int f = tid + (s<<8);
        int r = f >> 3;
        int c = (f & 7) << 2;
        float4 va = *(const float4*)(Ab + (size_t)(nt+r)*ND + kc + c);
        As[r][c]=va.x; As[r][c+1]=va.y; As[r][c+2]=va.z; As[r][c+3]=va.w;
        float4 vb = *(const float4*)(Bb + (size_t)(m0+r)*ND + kc + c);
        Bs[r][c]=vb.x; Bs[r][c+1]=vb.y; Bs[r][c+2]=vb.z; Bs[r][c+3]=vb.w;
      }
      __syncthreads();
      #pragma unroll 4
      for (int k=0;k<32;k++){
        float a0=As[ty*4+0][k], a1=As[ty*4+1][k], a2=As[ty*4+2][k], a3=As[ty*4+3][k];
        float b0=Bs[tx*4+0][k], b1=Bs[tx*4+1][k], b2=Bs[tx*4+2][k], b3=Bs[tx*4+3][k];
        acc[0][0]+=a0*b0; acc[0][1]+=a0*b1; acc[0][2]+=a0*b2; acc[0][3]+=a0*b3;
        acc[1][0]+=a1*b0; acc[1][1]+=a1*b1; acc[1][2]+=a1*b2; acc[1][3]+=a1*b3;
        acc[2][0]+=a2*b0; acc[2][1]+=a2*b1; acc[2][2]+=a2*b2; acc[2][3]+=a2*b3;
        acc[3][0]+=a3*b0; acc[3][1]+=a3*b1; acc[3][2]+=a3*b2; acc[3][3]+=a3*b3;
      }
    }
    float nlv[4];
    #pragma unroll
    for (int i=0;i<4;i++) nlv[i] = nl[b*NN + nt + ty*4 + i];
    __syncthreads();
    #pragma unroll
    for (int i=0;i<4;i++)
      #pragma unroll
      for (int j=0;j<4;j++){
        float denom = fmaxf(nlv[i]*nhv[j], 1e-8f);
        Cs[ty*4+i][tx*4+j] = (acc[i][j]/denom)*0.0625f;
      }
    __syncthreads();
    if (tid < 64){
      float tmax = -INFINITY;
      #pragma unroll 8
      for (int r=0;r<64;r++) tmax = fmaxf(tmax, Cs[r][tid]);
      float newM = fmaxf(Mr, tmax);
      float s = 0.0f;
      #pragma unroll 4
      for (int r=0;r<64;r++) s += expf(Cs[r][tid]-newM);
      Sr = Sr*expf(Mr-newM) + s;
      Mr = newM;
    }
  }
  if (tid < 64){
    Mout[b*NN+m0+tid] = Mr;
    Sinv[b*NN+m0+tid] = 1.0f/Sr;
  }
}

__launch_bounds__(256)
__global__ void kargmax(const float* __restrict__ A, const float* __restrict__ Bm,
                        const float* __restrict__ nl, const float* __restrict__ nh,
                        const float* __restrict__ Mv, const float* __restrict__ Sv,
                        int* __restrict__ idxout){
  __shared__ float As[64][33];
  __shared__ float Bs[64][33];
  __shared__ float Vs[16][64];
  __shared__ int   Is[16][64];
  const int b  = blockIdx.x >> 5;
  const int m0 = (blockIdx.x & 31) << 6;
  const float* Ab = A  + (size_t)b*NN*ND;
  const float* Bb = Bm + (size_t)b*NN*ND;
  const int tid = threadIdx.x;
  const int tx = tid & 15, ty = tid >> 4;
  float nhv[4], Mj[4], iSj[4];
  #pragma unroll
  for (int j=0;j<4;j++){
    int m = m0 + tx*4 + j;
    nhv[j] = nh[b*NN + m];
    Mj[j]  = Mv[b*NN + m];
    iSj[j] = Sv[b*NN + m];
  }
  float bestV = -INFINITY; int bestN = 0;
  for (int nt=0; nt<NN; nt+=64){
    float acc[4][4] = {{0.f,0.f,0.f,0.f},{0.f,0.f,0.f,0.f},{0.f,0.f,0.f,0.f},{0.f,0.f,0.f,0.f}};
    for (int kc=0; kc<ND; kc+=32){
      __syncthreads();
      #pragma unroll
      for (int s=0;s<2;s++){
        int f = tid + (s<<8);
        int r = f >> 3;
        int c = (f & 7) << 2;
        float4 va = *(const float4*)(Ab + (size_t)(nt+r)*ND + kc + c);
        As[r][c]=va.x; As[r][c+1]=va.y; As[r][c+2]=va.z; As[r][c+3]=va.w;
        float4 vb = *(const float4*)(Bb + (size_t)(m0+r)*ND + kc + c);
        Bs[r][c]=vb.x; Bs[r][c+1]=vb.y; Bs[r][c+2]=vb.z; Bs[r][c+3]=vb.w;
      }
      __syncthreads();
      #pragma unroll 4
      for (int k=0;k<32;k++){
        float a0=As[ty*4+0][k], a1=As[ty*4+1][k], a2=As[ty*4+2][k], a3=As[ty*4+3][k];
        float b0=Bs[tx*4+0][k], b1=Bs[tx*4+1][k], b2=Bs[tx*4+2][k], b3=Bs[tx*4+3][k];
        acc[0][0]+=a0*b0; acc[0][1]+=a0*b1; acc[0][2]+=a0*b2; acc[0][3]+=a0*b3;
        acc[1][0]+=a1*b0; acc[1][1]+=a1*b1; acc[1][2]+=a1*b2; acc[1][3]+=a1*b3;
        acc[2][0]+=a2*b0; acc[2][1]+=a2*b1; acc[2][2]+=a2*b2; acc[2][3]+=a2*b3;
        acc[3][0]+=a3*b0; acc[3][1]+=a3*b1; acc[3][2]+=a3*b2; acc[3][3]+=a3*b3;
      }
    }
    float nlv[4];
    #pragma unroll
    for (int i=0;i<4;i++) nlv[i] = nl[b*NN + nt + ty*4 + i];
    float lv[4]; int li[4];
    #pragma unroll
    for (int j=0;j<4;j++){ lv[j] = -INFINITY; li[j] = 0; }
    #pragma unroll
    for (int i=0;i<4;i++){
      int n = nt + ty*4 + i;
      #pragma unroll
      for (int j=0;j<4;j++){
        float denom = fmaxf(nlv[i]*nhv[j], 1e-8f);
        float sim = (acc[i][j]/denom)*0.0625f;
        float p = expf(sim - Mj[j]) * iSj[j];
        float v = p + gumbelv((unsigned)b, (unsigned)n, (unsigned)(m0 + tx*4 + j));
        if (v > lv[j]) { lv[j] = v; li[j] = n; }
      }
    }
    __syncthreads();
    #pragma unroll
    for (int j=0;j<4;j++){ Vs[ty][tx*4+j]=lv[j]; Is[ty][tx*4+j]=li[j]; }
    __syncthreads();
    if (tid < 64){
      #pragma unroll 4
      for (int t=0;t<16;t++){
        float v = Vs[t][tid];
        if (v > bestV){ bestV = v; bestN = Is[t][tid]; }
      }
    }
  }
  if (tid < 64) idxout[b*NN + m0 + tid] = bestN;
}

// ---------------- shared tail kernels ----------------
__global__ void ksort(const int* __restrict__ idx, int* __restrict__ cntg,
                      int* __restrict__ offg, int* __restrict__ sl){
  __shared__ int c[NN];
  __shared__ int part[256];
  int b = blockIdx.x, tid = threadIdx.x;
  for (int v=tid; v<NN; v+=256) c[v]=0;
  __syncthreads();
  for (int j=tid; j<NN; j+=256) atomicAdd(&c[idx[b*NN+j]], 1);
  __syncthreads();
  int base = tid*8, s=0, lc[8];
  #pragma unroll
  for (int k=0;k<8;k++){ lc[k]=c[base+k]; s+=lc[k]; }
  part[tid]=s; __syncthreads();
  for (int o=1;o<256;o<<=1){
    int v = (tid>=o)? part[tid-o] : 0;
    __syncthreads();
    part[tid]+=v;
    __syncthreads();
  }
  int run = part[tid]-s;
  #pragma unroll
  for (int k=0;k<8;k++){
    int v = base+k;
    cntg[b*NN+v]=lc[k];
    offg[b*NN+v]=run;
    for (int j=0;j<lc[k];j++) sl[b*NN+run+j]=v;
    run += lc[k];
  }
}

__global__ void kw(const float* __restrict__ LLF, const float* __restrict__ HLF,
                   const float* __restrict__ nl, const float* __restrict__ nh,
                   const int* __restrict__ sl, float* __restrict__ w){
  int g = blockIdx.x*4 + (threadIdx.x>>6);
  int lane = threadIdx.x & 63;
  int b = g >> 11;
  int s = sl[g];
  float4 a = ((const float4*)(HLF + ((size_t)b*NN + s)*ND))[lane];
  float4 l = ((const float4*)(LLF + (size_t)g*ND))[lane];
  float d = a.x*l.x + a.y*l.y + a.z*l.z + a.w*l.w;
  for (int o=32;o;o>>=1) d += __shfl_down(d,o);
  if (lane==0){
    float denom = fmaxf(nh[b*NN+s]*nl[g], 1e-8f);
    w[g] = d/denom;
  }
}

__global__ void knoise(const float* __restrict__ w, float* __restrict__ nz){
  int b = blockIdx.x, tid = threadIdx.x;
  __shared__ float sred[4];
  float x[8]; float mx = -INFINITY;
  #pragma unroll
  for (int k=0;k<8;k++){ x[k] = w[b*NN + tid*8 + k] / 0.1f; mx = fmaxf(mx, x[k]); }
  for (int o=32;o;o>>=1) mx = fmaxf(mx, __shfl_down(mx,o));
  mx = __shfl(mx, 0);
  if ((tid&63)==0) sred[tid>>6] = mx;
  __syncthreads();
  mx = fmaxf(fmaxf(sred[0],sred[1]), fmaxf(sred[2],sred[3]));
  __syncthreads();
  float e[8]; float s = 0.f;
  #pragma unroll
  for (int k=0;k<8;k++){ e[k] = expf(x[k]-mx); s += e[k]; }
  for (int o=32;o;o>>=1) s += __shfl_down(s,o);
  s = __shfl(s, 0);
  if ((tid&63)==0) sred[tid>>6] = s;
  __syncthreads();
  s = sred[0]+sred[1]+sred[2]+sred[3];
  #pragma unroll
  for (int k=0;k<8;k++) nz[b*NN + tid*8 + k] = e[k]/s;
}

__global__ void kfinal(const float* __restrict__ LLF, const float* __restrict__ HLF,
                       const int* __restrict__ cnt, const int* __restrict__ off,
                       const float* __restrict__ nz, float* __restrict__ out){
  int row = blockIdx.x;
  int lane = threadIdx.x;
  int b = row >> 11;
  float4 h = ((const float4*)(HLF + (size_t)row*ND))[lane];
  int c = cnt[row];
  if (c > 0){
    int i = off[row] + c - 1;
    float ns = nz[b*NN + i];
    float4 l = ((const float4*)(LLF + ((size_t)(b*NN + i))*ND))[lane];
    h.x += l.x*ns; h.y += l.y*ns; h.z += l.z*ns; h.w += l.w*ns;
  }
  ((float4*)(out + (size_t)row*ND))[lane] = h;
}

extern "C" void kernel_launch(void* const* d_in, const int* in_sizes, int n_in,
                              void* d_out, int out_size, void* d_ws, size_t ws_size,
                              hipStream_t stream){
  const float* LLF = (const float*)d_in[0];
  const float* HLF = (const float*)d_in[1];
  float* out = (float*)d_out;
  float* ws = (float*)d_ws;

  float* nl  = ws;
  float* nh  = ws + 1*(size_t)BNtot;
  float* iS  = ws + 2*(size_t)BNtot;                   // last-resort tier only
  int*   idx = (int*)(ws + 3*(size_t)BNtot);
  int*   cnt = (int*)(ws + 4*(size_t)BNtot);
  int*   off = (int*)(ws + 5*(size_t)BNtot);
  int*   sl  = (int*)(ws + 6*(size_t)BNtot);
  float* wv  = ws + 7*(size_t)BNtot;
  float* nz  = ws + 8*(size_t)BNtot;
  unsigned* pck = (unsigned*)(ws + 9*(size_t)BNtot);   // 32*BNtot packed candidates (4.2 MB)
  const size_t needA = (9 + 32) * (size_t)BNtot * 4;   // ~5.4 MB

  if (ws_size >= needA){
    // [norms + full gumbel] -> interval-resolve (no GEMM, no softmax denominators)
    hipLaunchKernelGGL(kfuse1,  dim3(2048),    dim3(256), 0, stream, LLF, HLF, nl, nh, pck);
    hipLaunchKernelGGL(kresolve,dim3(BNtot/4), dim3(256), 0, stream, LLF, HLF, nl, nh, pck, idx);
  } else {
    float* Mv = ws + 9*(size_t)BNtot;
    hipLaunchKernelGGL(knorms,   dim3(BNtot),    dim3(128), 0, stream, LLF, HLF, nl, nh);
    hipLaunchKernelGGL(kstats,   dim3(NB*32),    dim3(256), 0, stream, LLF, HLF, nl, nh, Mv, iS);
    hipLaunchKernelGGL(kargmax,  dim3(NB*32),    dim3(256), 0, stream, LLF, HLF, nl, nh, Mv, iS, idx);
  }

  hipLaunchKernelGGL(ksort,  dim3(NB),      dim3(256), 0, stream, idx, cnt, off, sl);
  hipLaunchKernelGGL(kw,     dim3(BNtot/4), dim3(256), 0, stream, LLF, HLF, nl, nh, sl, wv);
  hipLaunchKernelGGL(knoise, dim3(NB),      dim3(256), 0, stream, wv, nz);
  hipLaunchKernelGGL(kfinal, dim3(BNtot),   dim3(64),  0, stream, LLF, HLF, cnt, off, nz, out);
}

// Round 6
// 333.767 us; speedup vs baseline: 2.4311x; 2.4311x over previous
//
#include <hip/hip_runtime.h>
#include <math.h>

#define NB 16
#define NN 2048
#define ND 256
#define BNtot (NB*NN)
#define HH 33554432u   // 2^25 = half of 16*2048*2048 (threefry counter split)

__device__ __forceinline__ unsigned rotl(unsigned v, int r){
  return __builtin_amdgcn_alignbit(v, v, 32-r);   // single v_alignbit_b32
}
__device__ __forceinline__ unsigned umaxu(unsigned a, unsigned b){ return a > b ? a : b; }
__device__ __forceinline__ unsigned uminu(unsigned a, unsigned b){ return a < b ? a : b; }

// ---------------- threefry2x32, bit-exact vs jax.random.key(42) ----------------
__device__ __forceinline__ float gumbelv(unsigned b, unsigned n, unsigned m){
  unsigned f = (b<<22) | (n<<11) | m;
  unsigned x0 = (b < 8u) ? f : (f - HH);
  unsigned x1 = x0 + HH;
  const unsigned ks0=0u, ks1=42u, ks2=0u^42u^0x1BD11BDAu;
  unsigned v0 = x0 + ks0;
  unsigned v1 = x1 + ks1;
#define TFR(r) { v0 += v1; v1 = rotl(v1,(r)); v1 ^= v0; }
  TFR(13) TFR(15) TFR(26) TFR(6)
  v0 += ks1; v1 += ks2 + 1u;
  TFR(17) TFR(29) TFR(16) TFR(24)
  v0 += ks2; v1 += ks0 + 2u;
  TFR(13) TFR(15) TFR(26) TFR(6)
  v0 += ks0; v1 += ks1 + 3u;
  TFR(17) TFR(29) TFR(16) TFR(24)
  v0 += ks1; v1 += ks2 + 4u;
  TFR(13) TFR(15) TFR(26) TFR(6)
  v0 += ks2; v1 += ks0 + 5u;
#undef TFR
  unsigned bits = (b < 8u) ? v0 : v1;
  float fl = __uint_as_float((bits>>9) | 0x3F800000u) - 1.0f;
  float u = fmaxf(1e-10f, fl + 1e-10f);
  return -logf(-logf(u));
}

// g from 23-bit key, exactly as JAX: fl = as_float(key|0x3f800000)-1
__device__ __forceinline__ float gfromkey(unsigned key){
  float fl = __uint_as_float(key | 0x3F800000u) - 1.0f;
  float u = fmaxf(1e-10f, fl + 1e-10f);
  return -logf(-logf(u));
}

// ---------------- gumbel scan state ----------------
// Task t scans 64 of a 128-chunk's values (half = t&1); lane-pairs merge via
// shfl_xor(1). packed cand = (key bits 31..9) | vk, vk = 7-bit descending counter:
// integer max = max gumbel, ties -> smallest n. 16 chunks x top-2 = 32 candidates
// per (b,m) column, stored TRANSPOSED: pck[(b*NN+m)*32 + nq*2 + rank] so the
// consumer's 32-candidate read is one coalesced 128B wave load.
struct GumState {
  unsigned x0, vk, a1, a2, c1, c2;
  int t;
};

__device__ __forceinline__ void gum_init(GumState& g, int t){
  g.t = t;
  int half = t & 1;
  int m    = (t >> 1) & 2047;
  int bl   = (t >> 12) & 7;
  int nq   = t >> 15;                        // 0..15, chunk of 128
  int nstart = (nq << 7) + (half << 6);      // this thread's 64 values
  g.x0 = ((unsigned)bl << 22) | ((unsigned)nstart << 11) | (unsigned)m;
  g.a1 = g.a2 = g.c1 = g.c2 = 0;
  g.vk = (unsigned)(127 - (half<<6));        // descending; n = chunkbase + 127 - vk
}

__device__ __forceinline__ void gum_iter(GumState& g, const int cnt){
  const unsigned KS2 = 42u ^ 0x1BD11BDAu;
  unsigned x0=g.x0, vk=g.vk, a1=g.a1, a2=g.a2, c1=g.c1, c2=g.c2;
#define TFR(r)       { v0 += v1; v1 = rotl(v1,(r)); v1 ^= v0; }
#define TFRI(r, inj) { v0 += v1 + (inj); v1 = rotl(v1,(r)); v1 ^= v0; }
  #pragma unroll 4
  for (int j = 0; j < cnt; ++j){
    unsigned v0 = x0;
    unsigned v1 = x0 + (HH + 42u);
    TFR(13) TFR(15) TFR(26) TFR(6)
    v1 += KS2 + 1u;
    TFRI(17, 42u) TFR(29) TFR(16) TFR(24)
    v1 += 2u;
    TFRI(13, KS2) TFR(15) TFR(26) TFR(6)
    v1 += 42u + 3u;
    TFR(17) TFR(29) TFR(16) TFR(24)     /* v0 += 0 before this group */
    v1 += KS2 + 4u;
    TFRI(13, 42u) TFR(15) TFR(26) TFR(6)
    v0 += KS2; v1 += 5u;
    unsigned pa = (v0 & 0xFFFFFE00u) | vk;   // v_and_or_b32
    unsigned pb = (v1 & 0xFFFFFE00u) | vk;
    unsigned ta = uminu(pa, a1);
    a1 = umaxu(pa, a1);
    a2 = umaxu(ta, a2);
    unsigned tc = uminu(pb, c1);
    c1 = umaxu(pb, c1);
    c2 = umaxu(tc, c2);
    x0 += 2048u;
    vk -= 1u;
  }
#undef TFR
#undef TFRI
  g.x0=x0; g.vk=vk; g.a1=a1; g.a2=a2; g.c1=c1; g.c2=c2;
}

__device__ __forceinline__ void gum_finish(const GumState& g, unsigned* __restrict__ pck){
  int half = g.t & 1;
  int m    = (g.t >> 1) & 2047;
  int bl   = (g.t >> 12) & 7;
  int nq   = g.t >> 15;
  // merge with partner lane (other half of the chunk)
  unsigned p1 = __shfl_xor((int)g.a1, 1), p2 = __shfl_xor((int)g.a2, 1);
  unsigned q1 = __shfl_xor((int)g.c1, 1), q2 = __shfl_xor((int)g.c2, 1);
  unsigned A1 = umaxu(g.a1, p1);
  unsigned A2 = umaxu(uminu(g.a1, p1), umaxu(g.a2, p2));
  unsigned C1 = umaxu(g.c1, q1);
  unsigned C2 = umaxu(uminu(g.c1, q1), umaxu(g.c2, q2));
  if (half == 0){
    uint2 ua; ua.x = A1; ua.y = A2;
    uint2 uc; uc.x = C1; uc.y = C2;
    *(uint2*)(&pck[((size_t)bl*NN + m)*32 + (nq<<1)])     = ua;   // batch bl
    *(uint2*)(&pck[((size_t)(bl+8)*NN + m)*32 + (nq<<1)]) = uc;   // batch bl+8
  }
}

// norms for 4 rows held in registers: wave shuffle-reduce (same order as knorms)
__device__ __forceinline__ void norm_rows(const float4* v, int wid, int lane,
                                          float* __restrict__ nrm){
  #pragma unroll
  for (int i=0;i<4;i++){
    float s = v[i].x*v[i].x + v[i].y*v[i].y + v[i].z*v[i].z + v[i].w*v[i].w;
    for (int o=32;o;o>>=1) s += __shfl_down(s,o);
    if (lane==0) nrm[wid*4 + i] = sqrtf(s);
  }
}

// ---------------- row norms (last-resort tier) ----------------
__global__ void knorms(const float* __restrict__ LLF, const float* __restrict__ HLF,
                       float* __restrict__ nl, float* __restrict__ nh){
  int row = blockIdx.x;
  int wave = threadIdx.x >> 6;
  int lane = threadIdx.x & 63;
  const float* src = wave ? HLF : LLF;
  float4 v = ((const float4*)(src + (size_t)row*ND))[lane];
  float s = v.x*v.x + v.y*v.y + v.z*v.z + v.w*v.w;
  for (int o=32;o;o>>=1) s += __shfl_down(s,o);
  if (lane==0) (wave? nh: nl)[row] = sqrtf(s);
}

// ---------------- fused kernel 1: norms + full gumbel (thread-granular, R3-proven) ----------------
// 2048 blocks x 256 thr = 8192 waves = 32 waves/CU: whole grid resident from t=0,
// retires together. Each wave norms 4 LLF + 4 HLF rows; loads issued ahead of
// 32-iter gumbel chunks which hide the HBM latency.
__launch_bounds__(256, 8)
__global__ void kfuse1(const float* __restrict__ LLF, const float* __restrict__ HLF,
                       float* __restrict__ nl, float* __restrict__ nh,
                       unsigned* __restrict__ pck){
  int t = blockIdx.x*256 + (int)threadIdx.x;
  int wid = t >> 6;
  int lane = t & 63;
  GumState g; gum_init(g, t);
  float4 va[4];
  #pragma unroll
  for (int i=0;i<4;i++)
    va[i] = ((const float4*)(LLF + (size_t)(wid*4+i)*ND))[lane];
  gum_iter(g, 32);
  norm_rows(va, wid, lane, nl);
  float4 vb[4];
  #pragma unroll
  for (int i=0;i<4;i++)
    vb[i] = ((const float4*)(HLF + (size_t)(wid*4+i)*ND))[lane];
  gum_iter(g, 32);
  norm_rows(vb, wid, lane, nh);
  gum_finish(g, pck);
}

// ---------------- resolve: interval-argmax over 32 packed candidates ----------------
// Math: sim = cos/16 in [-1/16,1/16] exactly, so e_n = exp(sim-1/16) in [0.8825,1]
// and invS = 1/sum(e_n) in [1/2048, e^0.125/2048]. Column prob spread <=
// IHI*0.1175 = 6.5e-5 < the 8e-5 candidate window. q_i(invS) = e_i*invS + g_i is
// linear in invS: if the argmax at both interval endpoints agrees, it is the
// argmax for the true invS (pairwise dominance). Fast path (one candidate in
// window, ~all columns): no dots, no softmax at all.
// Exact fallback (deterministically ~1-3 columns/run): WAVE-PARALLEL column sum —
// h staged in per-wave LDS, each lane computes full 256-dim dots for 32 rows
// (R5 post-mortem: the serial wave-dot version was ~600us for ONE wave; this is
// ~10us and was the entire 811->~220 regression).
#define ILO 4.882e-4f
#define IHI 5.534e-4f
__launch_bounds__(256)
__global__ void kresolve(const float* __restrict__ LLF, const float* __restrict__ HLF,
                         const float* __restrict__ nl, const float* __restrict__ nh,
                         const unsigned* __restrict__ pck,
                         int* __restrict__ idx){
  __shared__ float hsAll[4][ND];             // 4 KB: per-wave h staging (fallback only)
  int w    = threadIdx.x >> 6;               // wave within block
  int lane = threadIdx.x & 63;
  int g = blockIdx.x*4 + w;                  // b*NN+m
  int b = g >> 11;
  float pv = -INFINITY; int pn = 0;
  if (lane < 32){                            // candidate c = lane: nq = c>>1, rank = c&1
    unsigned pk = pck[(size_t)g*32 + lane];  // coalesced 128B per wave
    pv = gfromkey(pk >> 9);
    pn = ((lane >> 1) << 7) + 127 - (int)(pk & 127u);
  }
  float gmax = pv;
  for (int o=32;o;o>>=1) gmax = fmaxf(gmax, __shfl_down(gmax,o));
  gmax = __shfl(gmax, 0);
  unsigned long long mask = __ballot(pv >= gmax - 8e-5f) & 0xFFFFFFFFull;
  if (__popcll(mask) == 1){
    int src = __builtin_ctzll(mask);
    int n = __shfl(pn, src);
    if (lane==0) idx[g] = n;
    return;
  }
  // ---- multi-candidate (expected ~3 columns of 32768): fp32 dots + endpoint test
  float4 h = ((const float4*)(HLF + (size_t)g*ND))[lane];
  float nhg = nh[g];
  float bestLo = -INFINITY, bestHi = -INFINITY;
  int nLo = 1<<30, nHi = 1<<30;
  unsigned long long mm = mask;
  while (mm){
    int src = __builtin_ctzll(mm); mm &= mm-1;
    int   n  = __shfl(pn, src);
    float gv = __shfl(pv, src);
    float4 a = ((const float4*)(LLF + ((size_t)b*NN + n)*ND))[lane];
    float d = a.x*h.x + a.y*h.y + a.z*h.z + a.w*h.w;
    for (int o=32;o;o>>=1) d += __shfl_down(d,o);
    d = __shfl(d, 0);
    float sim = (d / fmaxf(nl[b*NN+n]*nhg, 1e-8f)) * 0.0625f;
    float e = expf(sim - 0.0625f);
    float qlo = e*ILO + gv;
    float qhi = e*IHI + gv;
    if (qlo > bestLo || (qlo == bestLo && n < nLo)){ bestLo = qlo; nLo = n; }
    if (qhi > bestHi || (qhi == bestHi && n < nHi)){ bestHi = qhi; nHi = n; }
  }
  if (nLo == nHi){
    if (lane==0) idx[g] = nLo;
    return;
  }
  // ---- exact fallback: wave-parallel column softmax denominator.
  // h row (1KB) -> this wave's LDS slot; each lane owns rows n2 = r*64+lane,
  // 4 independent FMA chains over k. All traffic is L2/L3-resident.
  float* hs = hsAll[w];
  *(float4*)(&hs[lane<<2]) = h;              // same-wave ds_write->ds_read, compiler waits lgkm
  float S = 0.0f;
  for (int r = 0; r < 32; ++r){
    int n2 = (r<<6) + lane;
    const float4* ap = (const float4*)(LLF + ((size_t)b*NN + n2)*ND);
    float dd0=0.f, dd1=0.f, dd2=0.f, dd3=0.f;
    #pragma unroll 4
    for (int k=0;k<64;k+=4){
      float4 a0=ap[k], a1=ap[k+1], a2=ap[k+2], a3=ap[k+3];
      dd0 += a0.x*hs[4*k+ 0]+a0.y*hs[4*k+ 1]+a0.z*hs[4*k+ 2]+a0.w*hs[4*k+ 3];
      dd1 += a1.x*hs[4*k+ 4]+a1.y*hs[4*k+ 5]+a1.z*hs[4*k+ 6]+a1.w*hs[4*k+ 7];
      dd2 += a2.x*hs[4*k+ 8]+a2.y*hs[4*k+ 9]+a2.z*hs[4*k+10]+a2.w*hs[4*k+11];
      dd3 += a3.x*hs[4*k+12]+a3.y*hs[4*k+13]+a3.z*hs[4*k+14]+a3.w*hs[4*k+15];
    }
    float d = (dd0+dd1)+(dd2+dd3);
    float sim = (d / fmaxf(nl[b*NN+n2]*nhg, 1e-8f)) * 0.0625f;
    S += expf(sim - 0.0625f);
  }
  for (int o=32;o;o>>=1) S += __shfl_down(S,o);
  S = __shfl(S, 0);
  float invS = 1.0f / S;
  float bestQ = -INFINITY; int bestN = 1<<30;
  mm = mask;
  while (mm){
    int src = __builtin_ctzll(mm); mm &= mm-1;
    int   n  = __shfl(pn, src);
    float gv = __shfl(pv, src);
    float4 a = ((const float4*)(LLF + ((size_t)b*NN + n)*ND))[lane];
    float d = a.x*h.x + a.y*h.y + a.z*h.z + a.w*h.w;
    for (int o=32;o;o>>=1) d += __shfl_down(d,o);
    d = __shfl(d, 0);
    float sim = (d / fmaxf(nl[b*NN+n]*nhg, 1e-8f)) * 0.0625f;
    float q = expf(sim - 0.0625f)*invS + gv;
    if (q > bestQ || (q == bestQ && n < bestN)){ bestQ = q; bestN = n; }
  }
  if (lane==0) idx[g] = bestN;
}

// ---------------- last-resort fallback (tiny ws) ----------------
__launch_bounds__(256)
__global__ void kstats(const float* __restrict__ A, const float* __restrict__ Bm,
                       const float* __restrict__ nl, const float* __restrict__ nh,
                       float* __restrict__ Mout, float* __restrict__ Sinv){
  __shared__ float As[64][33];
  __shared__ float Bs[64][33];
  __shared__ float Cs[64][65];
  const int b  = blockIdx.x >> 5;
  const int m0 = (blockIdx.x & 31) << 6;
  const float* Ab = A  + (size_t)b*NN*ND;
  const float* Bb = Bm + (size_t)b*NN*ND;
  const int tid = threadIdx.x;
  const int tx = tid & 15, ty = tid >> 4;
  float nhv[4];
  #pragma unroll
  for (int j=0;j<4;j++) nhv[j] = nh[b*NN + m0 + tx*4 + j];
  float Mr = -INFINITY, Sr = 0.0f;
  for (int nt=0; nt<NN; nt+=64){
    float acc[4][4] = {{0.f,0.f,0.f,0.f},{0.f,0.f,0.f,0.f},{0.f,0.f,0.f,0.f},{0.f,0.f,0.f,0.f}};
    for (int kc=0; kc<ND; kc+=32){
      __syncthreads();
      #pragma unroll
      for (int s=0;s<2;s++){
        int f = tid + (s<<8);
        int r = f >> 3;
        int c = (f & 7) << 2;
        float4 va = *(const float4*)(Ab + (size_t)(nt+r)*ND + kc + c);
        As[r][c]=va.x; As[r][c+1]=va.y; As[r][c+2]=va.z; As[r][c+3]=va.w;
        float4 vb = *(const float4*)(Bb + (size_t)(m0+r)*ND + kc + c);
        Bs[r][c]=vb.x; Bs[r][c+1]=vb.y; Bs[r][c+2]=vb.z; Bs[r][c+3]=vb.w;
      }
      __syncthreads();
      #pragma unroll 4
      for (int k=0;k<32;k++){
        float a0=As[ty*4+0][k], a1=As[ty*4+1][k], a2=As[ty*4+2][k], a3=As[ty*4+3][k];
        float b0=Bs[tx*4+0][k], b1=Bs[tx*4+1][k], b2=Bs[tx*4+2][k], b3=Bs[tx*4+3][k];
        acc[0][0]+=a0*b0; acc[0][1]+=a0*b1; acc[0][2]+=a0*b2; acc[0][3]+=a0*b3;
        acc[1][0]+=a1*b0; acc[1][1]+=a1*b1; acc[1][2]+=a1*b2; acc[1][3]+=a1*b3;
        acc[2][0]+=a2*b0; acc[2][1]+=a2*b1; acc[2][2]+=a2*b2; acc[2][3]+=a2*b3;
        acc[3][0]+=a3*b0; acc[3][1]+=a3*b1; acc[3][2]+=a3*b2; acc[3][3]+=a3*b3;
      }
    }
    float nlv[4];
    #pragma unroll
    for (int i=0;i<4;i++) nlv[i] = nl[b*NN + nt + ty*4 + i];
    __syncthreads();
    #pragma unroll
    for (int i=0;i<4;i++)
      #pragma unroll
      for (int j=0;j<4;j++){
        float denom = fmaxf(nlv[i]*nhv[j], 1e-8f);
        Cs[ty*4+i][tx*4+j] = (acc[i][j]/denom)*0.0625f;
      }
    __syncthreads();
    if (tid < 64){
      float tmax = -INFINITY;
      #pragma unroll 8
      for (int r=0;r<64;r++) tmax = fmaxf(tmax, Cs[r][tid]);
      float newM = fmaxf(Mr, tmax);
      float s = 0.0f;
      #pragma unroll 4
      for (int r=0;r<64;r++) s += expf(Cs[r][tid]-newM);
      Sr = Sr*expf(Mr-newM) + s;
      Mr = newM;
    }
  }
  if (tid < 64){
    Mout[b*NN+m0+tid] = Mr;
    Sinv[b*NN+m0+tid] = 1.0f/Sr;
  }
}

__launch_bounds__(256)
__global__ void kargmax(const float* __restrict__ A, const float* __restrict__ Bm,
                        const float* __restrict__ nl, const float* __restrict__ nh,
                        const float* __restrict__ Mv, const float* __restrict__ Sv,
                        int* __restrict__ idxout){
  __shared__ float As[64][33];
  __shared__ float Bs[64][33];
  __shared__ float Vs[16][64];
  __shared__ int   Is[16][64];
  const int b  = blockIdx.x >> 5;
  const int m0 = (blockIdx.x & 31) << 6;
  const float* Ab = A  + (size_t)b*NN*ND;
  const float* Bb = Bm + (size_t)b*NN*ND;
  const int tid = threadIdx.x;
  const int tx = tid & 15, ty = tid >> 4;
  float nhv[4], Mj[4], iSj[4];
  #pragma unroll
  for (int j=0;j<4;j++){
    int m = m0 + tx*4 + j;
    nhv[j] = nh[b*NN + m];
    Mj[j]  = Mv[b*NN + m];
    iSj[j] = Sv[b*NN + m];
  }
  float bestV = -INFINITY; int bestN = 0;
  for (int nt=0; nt<NN; nt+=64){
    float acc[4][4] = {{0.f,0.f,0.f,0.f},{0.f,0.f,0.f,0.f},{0.f,0.f,0.f,0.f},{0.f,0.f,0.f,0.f}};
    for (int kc=0; kc<ND; kc+=32){
      __syncthreads();
      #pragma unroll
      for (int s=0;s<2;s++){
        int f = tid + (s<<8);
        int r = f >> 3;
        int c = (f & 7) << 2;
        float4 va = *(const float4*)(Ab + (size_t)(nt+r)*ND + kc + c);
        As[r][c]=va.x; As[r][c+1]=va.y; As[r][c+2]=va.z; As[r][c+3]=va.w;
        float4 vb = *(const float4*)(Bb + (size_t)(m0+r)*ND + kc + c);
        Bs[r][c]=vb.x; Bs[r][c+1]=vb.y; Bs[r][c+2]=vb.z; Bs[r][c+3]=vb.w;
      }
      __syncthreads();
      #pragma unroll 4
      for (int k=0;k<32;k++){
        float a0=As[ty*4+0][k], a1=As[ty*4+1][k], a2=As[ty*4+2][k], a3=As[ty*4+3][k];
        float b0=Bs[tx*4+0][k], b1=Bs[tx*4+1][k], b2=Bs[tx*4+2][k], b3=Bs[tx*4+3][k];
        acc[0][0]+=a0*b0; acc[0][1]+=a0*b1; acc[0][2]+=a0*b2; acc[0][3]+=a0*b3;
        acc[1][0]+=a1*b0; acc[1][1]+=a1*b1; acc[1][2]+=a1*b2; acc[1][3]+=a1*b3;
        acc[2][0]+=a2*b0; acc[2][1]+=a2*b1; acc[2][2]+=a2*b2; acc[2][3]+=a2*b3;
        acc[3][0]+=a3*b0; acc[3][1]+=a3*b1; acc[3][2]+=a3*b2; acc[3][3]+=a3*b3;
      }
    }
    float nlv[4];
    #pragma unroll
    for (int i=0;i<4;i++) nlv[i] = nl[b*NN + nt + ty*4 + i];
    float lv[4]; int li[4];
    #pragma unroll
    for (int j=0;j<4;j++){ lv[j] = -INFINITY; li[j] = 0; }
    #pragma unroll
    for (int i=0;i<4;i++){
      int n = nt + ty*4 + i;
      #pragma unroll
      for (int j=0;j<4;j++){
        float denom = fmaxf(nlv[i]*nhv[j], 1e-8f);
        float sim = (acc[i][j]/denom)*0.0625f;
        float p = expf(sim - Mj[j]) * iSj[j];
        float v = p + gumbelv((unsigned)b, (unsigned)n, (unsigned)(m0 + tx*4 + j));
        if (v > lv[j]) { lv[j] = v; li[j] = n; }
      }
    }
    __syncthreads();
    #pragma unroll
    for (int j=0;j<4;j++){ Vs[ty][tx*4+j]=lv[j]; Is[ty][tx*4+j]=li[j]; }
    __syncthreads();
    if (tid < 64){
      #pragma unroll 4
      for (int t=0;t<16;t++){
        float v = Vs[t][tid];
        if (v > bestV){ bestV = v; bestN = Is[t][tid]; }
      }
    }
  }
  if (tid < 64) idxout[b*NN + m0 + tid] = bestN;
}

// ---------------- shared tail kernels ----------------
__global__ void ksort(const int* __restrict__ idx, int* __restrict__ cntg,
                      int* __restrict__ offg, int* __restrict__ sl){
  __shared__ int c[NN];
  __shared__ int part[256];
  int b = blockIdx.x, tid = threadIdx.x;
  for (int v=tid; v<NN; v+=256) c[v]=0;
  __syncthreads();
  for (int j=tid; j<NN; j+=256) atomicAdd(&c[idx[b*NN+j]], 1);
  __syncthreads();
  int base = tid*8, s=0, lc[8];
  #pragma unroll
  for (int k=0;k<8;k++){ lc[k]=c[base+k]; s+=lc[k]; }
  part[tid]=s; __syncthreads();
  for (int o=1;o<256;o<<=1){
    int v = (tid>=o)? part[tid-o] : 0;
    __syncthreads();
    part[tid]+=v;
    __syncthreads();
  }
  int run = part[tid]-s;
  #pragma unroll
  for (int k=0;k<8;k++){
    int v = base+k;
    cntg[b*NN+v]=lc[k];
    offg[b*NN+v]=run;
    for (int j=0;j<lc[k];j++) sl[b*NN+run+j]=v;
    run += lc[k];
  }
}

__global__ void kw(const float* __restrict__ LLF, const float* __restrict__ HLF,
                   const float* __restrict__ nl, const float* __restrict__ nh,
                   const int* __restrict__ sl, float* __restrict__ w){
  int g = blockIdx.x*4 + (threadIdx.x>>6);
  int lane = threadIdx.x & 63;
  int b = g >> 11;
  int s = sl[g];
  float4 a = ((const float4*)(HLF + ((size_t)b*NN + s)*ND))[lane];
  float4 l = ((const float4*)(LLF + (size_t)g*ND))[lane];
  float d = a.x*l.x + a.y*l.y + a.z*l.z + a.w*l.w;
  for (int o=32;o;o>>=1) d += __shfl_down(d,o);
  if (lane==0){
    float denom = fmaxf(nh[b*NN+s]*nl[g], 1e-8f);
    w[g] = d/denom;
  }
}

__global__ void knoise(const float* __restrict__ w, float* __restrict__ nz){
  int b = blockIdx.x, tid = threadIdx.x;
  __shared__ float sred[4];
  float x[8]; float mx = -INFINITY;
  #pragma unroll
  for (int k=0;k<8;k++){ x[k] = w[b*NN + tid*8 + k] / 0.1f; mx = fmaxf(mx, x[k]); }
  for (int o=32;o;o>>=1) mx = fmaxf(mx, __shfl_down(mx,o));
  mx = __shfl(mx, 0);
  if ((tid&63)==0) sred[tid>>6] = mx;
  __syncthreads();
  mx = fmaxf(fmaxf(sred[0],sred[1]), fmaxf(sred[2],sred[3]));
  __syncthreads();
  float e[8]; float s = 0.f;
  #pragma unroll
  for (int k=0;k<8;k++){ e[k] = expf(x[k]-mx); s += e[k]; }
  for (int o=32;o;o>>=1) s += __shfl_down(s,o);
  s = __shfl(s, 0);
  if ((tid&63)==0) sred[tid>>6] = s;
  __syncthreads();
  s = sred[0]+sred[1]+sred[2]+sred[3];
  #pragma unroll
  for (int k=0;k<8;k++) nz[b*NN + tid*8 + k] = e[k]/s;
}

__global__ void kfinal(const float* __restrict__ LLF, const float* __restrict__ HLF,
                       const int* __restrict__ cnt, const int* __restrict__ off,
                       const float* __restrict__ nz, float* __restrict__ out){
  int row = blockIdx.x;
  int lane = threadIdx.x;
  int b = row >> 11;
  float4 h = ((const float4*)(HLF + (size_t)row*ND))[lane];
  int c = cnt[row];
  if (c > 0){
    int i = off[row] + c - 1;
    float ns = nz[b*NN + i];
    float4 l = ((const float4*)(LLF + ((size_t)(b*NN + i))*ND))[lane];
    h.x += l.x*ns; h.y += l.y*ns; h.z += l.z*ns; h.w += l.w*ns;
  }
  ((float4*)(out + (size_t)row*ND))[lane] = h;
}

extern "C" void kernel_launch(void* const* d_in, const int* in_sizes, int n_in,
                              void* d_out, int out_size, void* d_ws, size_t ws_size,
                              hipStream_t stream){
  const float* LLF = (const float*)d_in[0];
  const float* HLF = (const float*)d_in[1];
  float* out = (float*)d_out;
  float* ws = (float*)d_ws;

  float* nl  = ws;
  float* nh  = ws + 1*(size_t)BNtot;
  float* iS  = ws + 2*(size_t)BNtot;                   // last-resort tier only
  int*   idx = (int*)(ws + 3*(size_t)BNtot);
  int*   cnt = (int*)(ws + 4*(size_t)BNtot);
  int*   off = (int*)(ws + 5*(size_t)BNtot);
  int*   sl  = (int*)(ws + 6*(size_t)BNtot);
  float* wv  = ws + 7*(size_t)BNtot;
  float* nz  = ws + 8*(size_t)BNtot;
  unsigned* pck = (unsigned*)(ws + 9*(size_t)BNtot);   // 32*BNtot packed candidates (4.2 MB)
  const size_t needA = (9 + 32) * (size_t)BNtot * 4;   // ~5.4 MB

  if (ws_size >= needA){
    // [norms + full gumbel] -> interval-resolve (no GEMM, no softmax denominators)
    hipLaunchKernelGGL(kfuse1,  dim3(2048),    dim3(256), 0, stream, LLF, HLF, nl, nh, pck);
    hipLaunchKernelGGL(kresolve,dim3(BNtot/4), dim3(256), 0, stream, LLF, HLF, nl, nh, pck, idx);
  } else {
    float* Mv = ws + 9*(size_t)BNtot;
    hipLaunchKernelGGL(knorms,   dim3(BNtot),    dim3(128), 0, stream, LLF, HLF, nl, nh);
    hipLaunchKernelGGL(kstats,   dim3(NB*32),    dim3(256), 0, stream, LLF, HLF, nl, nh, Mv, iS);
    hipLaunchKernelGGL(kargmax,  dim3(NB*32),    dim3(256), 0, stream, LLF, HLF, nl, nh, Mv, iS, idx);
  }

  hipLaunchKernelGGL(ksort,  dim3(NB),      dim3(256), 0, stream, idx, cnt, off, sl);
  hipLaunchKernelGGL(kw,     dim3(BNtot/4), dim3(256), 0, stream, LLF, HLF, nl, nh, sl, wv);
  hipLaunchKernelGGL(knoise, dim3(NB),      dim3(256), 0, stream, wv, nz);
  hipLaunchKernelGGL(kfinal, dim3(BNtot),   dim3(64),  0, stream, LLF, HLF, cnt, off, nz, out);
}

// Round 8
// 276.697 us; speedup vs baseline: 2.9326x; 1.2063x over previous
//
#include <hip/hip_runtime.h>
#include <math.h>

#define NB 16
#define NN 2048
#define ND 256
#define BNtot (NB*NN)
#define HH 33554432u   // 2^25 = half of 16*2048*2048 (threefry counter split)

__device__ __forceinline__ unsigned rotl(unsigned v, int r){
  return __builtin_amdgcn_alignbit(v, v, 32-r);   // single v_alignbit_b32
}
__device__ __forceinline__ unsigned umaxu(unsigned a, unsigned b){ return a > b ? a : b; }
__device__ __forceinline__ unsigned uminu(unsigned a, unsigned b){ return a < b ? a : b; }

// ---------------- threefry2x32, bit-exact vs jax.random.key(42) ----------------
__device__ __forceinline__ float gumbelv(unsigned b, unsigned n, unsigned m){
  unsigned f = (b<<22) | (n<<11) | m;
  unsigned x0 = (b < 8u) ? f : (f - HH);
  unsigned x1 = x0 + HH;
  const unsigned ks0=0u, ks1=42u, ks2=0u^42u^0x1BD11BDAu;
  unsigned v0 = x0 + ks0;
  unsigned v1 = x1 + ks1;
#define TFR(r) { v0 += v1; v1 = rotl(v1,(r)); v1 ^= v0; }
  TFR(13) TFR(15) TFR(26) TFR(6)
  v0 += ks1; v1 += ks2 + 1u;
  TFR(17) TFR(29) TFR(16) TFR(24)
  v0 += ks2; v1 += ks0 + 2u;
  TFR(13) TFR(15) TFR(26) TFR(6)
  v0 += ks0; v1 += ks1 + 3u;
  TFR(17) TFR(29) TFR(16) TFR(24)
  v0 += ks1; v1 += ks2 + 4u;
  TFR(13) TFR(15) TFR(26) TFR(6)
  v0 += ks2; v1 += ks0 + 5u;
#undef TFR
  unsigned bits = (b < 8u) ? v0 : v1;
  float fl = __uint_as_float((bits>>9) | 0x3F800000u) - 1.0f;
  float u = fmaxf(1e-10f, fl + 1e-10f);
  return -logf(-logf(u));
}

// g from 23-bit key, exactly as JAX: fl = as_float(key|0x3f800000)-1
__device__ __forceinline__ float gfromkey(unsigned key){
  float fl = __uint_as_float(key | 0x3F800000u) - 1.0f;
  float u = fmaxf(1e-10f, fl + 1e-10f);
  return -logf(-logf(u));
}

// ---------------- gumbel scan state ----------------
// Task t scans 64 of a 128-chunk's values (half = t&1); lane-pairs merge via
// shfl_xor(1). packed cand = (key bits 31..9) | vk, vk = 7-bit descending counter:
// integer max = max gumbel, ties -> smallest n. 16 chunks x top-2 = 32 candidates
// per (b,m) column, stored TRANSPOSED: pck[(b*NN+m)*32 + nq*2 + rank] so the
// consumer's 32-candidate read is one coalesced 128B wave load.
struct GumState {
  unsigned x0, vk, a1, a2, c1, c2;
  int t;
};

__device__ __forceinline__ void gum_init(GumState& g, int t){
  g.t = t;
  int half = t & 1;
  int m    = (t >> 1) & 2047;
  int bl   = (t >> 12) & 7;
  int nq   = t >> 15;                        // 0..15, chunk of 128
  int nstart = (nq << 7) + (half << 6);      // this thread's 64 values
  g.x0 = ((unsigned)bl << 22) | ((unsigned)nstart << 11) | (unsigned)m;
  g.a1 = g.a2 = g.c1 = g.c2 = 0;
  g.vk = (unsigned)(127 - (half<<6));        // descending; n = chunkbase + 127 - vk
}

__device__ __forceinline__ void gum_iter(GumState& g, const int cnt){
  const unsigned KS2 = 42u ^ 0x1BD11BDAu;
  unsigned x0=g.x0, vk=g.vk, a1=g.a1, a2=g.a2, c1=g.c1, c2=g.c2;
#define TFR(r)       { v0 += v1; v1 = rotl(v1,(r)); v1 ^= v0; }
#define TFRI(r, inj) { v0 += v1 + (inj); v1 = rotl(v1,(r)); v1 ^= v0; }
  #pragma unroll 4
  for (int j = 0; j < cnt; ++j){
    unsigned v0 = x0;
    unsigned v1 = x0 + (HH + 42u);
    TFR(13) TFR(15) TFR(26) TFR(6)
    v1 += KS2 + 1u;
    TFRI(17, 42u) TFR(29) TFR(16) TFR(24)
    v1 += 2u;
    TFRI(13, KS2) TFR(15) TFR(26) TFR(6)
    v1 += 42u + 3u;
    TFR(17) TFR(29) TFR(16) TFR(24)     /* v0 += 0 before this group */
    v1 += KS2 + 4u;
    TFRI(13, 42u) TFR(15) TFR(26) TFR(6)
    v0 += KS2; v1 += 5u;
    unsigned pa = (v0 & 0xFFFFFE00u) | vk;   // v_and_or_b32
    unsigned pb = (v1 & 0xFFFFFE00u) | vk;
    unsigned ta = uminu(pa, a1);
    a1 = umaxu(pa, a1);
    a2 = umaxu(ta, a2);
    unsigned tc = uminu(pb, c1);
    c1 = umaxu(pb, c1);
    c2 = umaxu(tc, c2);
    x0 += 2048u;
    vk -= 1u;
  }
#undef TFR
#undef TFRI
  g.x0=x0; g.vk=vk; g.a1=a1; g.a2=a2; g.c1=c1; g.c2=c2;
}

__device__ __forceinline__ void gum_finish(const GumState& g, unsigned* __restrict__ pck){
  int half = g.t & 1;
  int m    = (g.t >> 1) & 2047;
  int bl   = (g.t >> 12) & 7;
  int nq   = g.t >> 15;
  // merge with partner lane (other half of the chunk)
  unsigned p1 = __shfl_xor((int)g.a1, 1), p2 = __shfl_xor((int)g.a2, 1);
  unsigned q1 = __shfl_xor((int)g.c1, 1), q2 = __shfl_xor((int)g.c2, 1);
  unsigned A1 = umaxu(g.a1, p1);
  unsigned A2 = umaxu(uminu(g.a1, p1), umaxu(g.a2, p2));
  unsigned C1 = umaxu(g.c1, q1);
  unsigned C2 = umaxu(uminu(g.c1, q1), umaxu(g.c2, q2));
  if (half == 0){
    uint2 ua; ua.x = A1; ua.y = A2;
    uint2 uc; uc.x = C1; uc.y = C2;
    *(uint2*)(&pck[((size_t)bl*NN + m)*32 + (nq<<1)])     = ua;   // batch bl
    *(uint2*)(&pck[((size_t)(bl+8)*NN + m)*32 + (nq<<1)]) = uc;   // batch bl+8
  }
}

// norms for 4 rows held in registers: wave shuffle-reduce (same order as knorms)
__device__ __forceinline__ void norm_rows(const float4* v, int wid, int lane,
                                          float* __restrict__ nrm){
  #pragma unroll
  for (int i=0;i<4;i++){
    float s = v[i].x*v[i].x + v[i].y*v[i].y + v[i].z*v[i].z + v[i].w*v[i].w;
    for (int o=32;o;o>>=1) s += __shfl_down(s,o);
    if (lane==0) nrm[wid*4 + i] = sqrtf(s);
  }
}

// ---------------- row norms (last-resort tier) ----------------
__global__ void knorms(const float* __restrict__ LLF, const float* __restrict__ HLF,
                       float* __restrict__ nl, float* __restrict__ nh){
  int row = blockIdx.x;
  int wave = threadIdx.x >> 6;
  int lane = threadIdx.x & 63;
  const float* src = wave ? HLF : LLF;
  float4 v = ((const float4*)(src + (size_t)row*ND))[lane];
  float s = v.x*v.x + v.y*v.y + v.z*v.z + v.w*v.w;
  for (int o=32;o;o>>=1) s += __shfl_down(s,o);
  if (lane==0) (wave? nh: nl)[row] = sqrtf(s);
}

// ---------------- fused kernel 1: norms + full gumbel (thread-granular, R3-proven) ----------------
// 2048 blocks x 256 thr = 8192 waves = 32 waves/CU: whole grid resident from t=0,
// retires together. Each wave norms 4 LLF + 4 HLF rows; loads issued ahead of
// 32-iter gumbel chunks which hide the HBM latency.
__launch_bounds__(256, 8)
__global__ void kfuse1(const float* __restrict__ LLF, const float* __restrict__ HLF,
                       float* __restrict__ nl, float* __restrict__ nh,
                       unsigned* __restrict__ pck){
  int t = blockIdx.x*256 + (int)threadIdx.x;
  int wid = t >> 6;
  int lane = t & 63;
  GumState g; gum_init(g, t);
  float4 va[4];
  #pragma unroll
  for (int i=0;i<4;i++)
    va[i] = ((const float4*)(LLF + (size_t)(wid*4+i)*ND))[lane];
  gum_iter(g, 32);
  norm_rows(va, wid, lane, nl);
  float4 vb[4];
  #pragma unroll
  for (int i=0;i<4;i++)
    vb[i] = ((const float4*)(HLF + (size_t)(wid*4+i)*ND))[lane];
  gum_iter(g, 32);
  norm_rows(vb, wid, lane, nh);
  gum_finish(g, pck);
}

// ---------------- resolve: interval-argmax over 32 packed candidates ----------------
// Math: sim = cos/16 in [-1/16,1/16] exactly, so e_n = exp(sim-1/16) in [0.8825,1]
// and invS = 1/sum(e_n) in [1/2048, e^0.125/2048]. q_i(invS) = e_i*invS + g_i is
// linear in invS: if the argmax at both interval endpoints agrees, it is the
// argmax for the true invS. Fast path (one candidate in window, ~all columns):
// no dots, no softmax at all.
// Exact fallback (deterministically ~1 column/run): BLOCK-COOPERATIVE column
// softmax denominator. R6 post-mortem: one WAVE doing this alone = 129us
// straggler (VALUBusy 3.5%, Occ 2.7%); all 256 threads + 4-wave TLP = ~8us.
// No early returns before the barrier: every wave posts need[w]; blocks with no
// needy wave exit uniformly after one barrier (noise across 8191 blocks).
#define ILO 4.882e-4f
#define IHI 5.534e-4f
__launch_bounds__(256)
__global__ void kresolve(const float* __restrict__ LLF, const float* __restrict__ HLF,
                         const float* __restrict__ nl, const float* __restrict__ nh,
                         const unsigned* __restrict__ pck,
                         int* __restrict__ idx){
  __shared__ float hsAll[4][ND];             // 4 KB: per-wave h staging (fallback only)
  __shared__ int   needLDS[4];
  __shared__ float Sres[4];
  int w    = threadIdx.x >> 6;               // wave within block
  int lane = threadIdx.x & 63;
  int g = blockIdx.x*4 + w;                  // b*NN+m
  int b = g >> 11;
  float pv = -INFINITY; int pn = 0;
  if (lane < 32){                            // candidate c = lane: nq = c>>1, rank = c&1
    unsigned pk = pck[(size_t)g*32 + lane];  // coalesced 128B per wave
    pv = gfromkey(pk >> 9);
    pn = ((lane >> 1) << 7) + 127 - (int)(pk & 127u);
  }
  float gmax = pv;
  for (int o=32;o;o>>=1) gmax = fmaxf(gmax, __shfl_down(gmax,o));
  gmax = __shfl(gmax, 0);
  unsigned long long mask = __ballot(pv >= gmax - 8e-5f) & 0xFFFFFFFFull;
  int resolved = -1;
  int need = -1;
  float4 h = {0.f,0.f,0.f,0.f};
  float nhg = 1.0f;
  if (__popcll(mask) == 1){
    int src = __builtin_ctzll(mask);
    resolved = __shfl(pn, src);
  } else {
    // multi-candidate (expected ~few columns of 32768): fp32 dots + endpoint test
    h = ((const float4*)(HLF + (size_t)g*ND))[lane];
    *(float4*)(&hsAll[w][lane<<2]) = h;      // stage h for possible cooperative phase
    nhg = nh[g];
    float bestLo = -INFINITY, bestHi = -INFINITY;
    int nLo = 1<<30, nHi = 1<<30;
    unsigned long long mm = mask;
    while (mm){
      int src = __builtin_ctzll(mm); mm &= mm-1;
      int   n  = __shfl(pn, src);
      float gv = __shfl(pv, src);
      float4 a = ((const float4*)(LLF + ((size_t)b*NN + n)*ND))[lane];
      float d = a.x*h.x + a.y*h.y + a.z*h.z + a.w*h.w;
      for (int o=32;o;o>>=1) d += __shfl_down(d,o);
      d = __shfl(d, 0);
      float sim = (d / fmaxf(nl[b*NN+n]*nhg, 1e-8f)) * 0.0625f;
      float e = expf(sim - 0.0625f);
      float qlo = e*ILO + gv;
      float qhi = e*IHI + gv;
      if (qlo > bestLo || (qlo == bestLo && n < nLo)){ bestLo = qlo; nLo = n; }
      if (qhi > bestHi || (qhi == bestHi && n < nHi)){ bestHi = qhi; nHi = n; }
    }
    if (nLo == nHi) resolved = nLo; else need = g;
  }
  if (resolved >= 0 && lane == 0) idx[g] = resolved;
  if (lane == 0) needLDS[w] = need;
  __syncthreads();
  int nm = needLDS[0] > needLDS[1] ? needLDS[0] : needLDS[1];
  int nm2 = needLDS[2] > needLDS[3] ? needLDS[2] : needLDS[3];
  if ((nm > nm2 ? nm : nm2) < 0) return;     // uniform: no needy wave in this block

  // ---- cooperative exact phase: all 256 threads compute S for each needy column
  for (int w2 = 0; w2 < 4; ++w2){
    int g2 = needLDS[w2];
    if (g2 < 0) continue;                    // uniform across block
    int b2 = g2 >> 11;
    float nh2 = nh[g2];
    const float* hs = hsAll[w2];
    float S = 0.0f;
    for (int r = 0; r < 8; ++r){
      int n2 = (r<<8) + (int)threadIdx.x;    // 8 rows per thread, 256 threads
      const float4* ap = (const float4*)(LLF + ((size_t)b2*NN + n2)*ND);
      float dd0=0.f, dd1=0.f, dd2=0.f, dd3=0.f;
      #pragma unroll 4
      for (int k=0;k<64;k+=4){
        float4 a0=ap[k], a1=ap[k+1], a2=ap[k+2], a3=ap[k+3];
        dd0 += a0.x*hs[4*k+ 0]+a0.y*hs[4*k+ 1]+a0.z*hs[4*k+ 2]+a0.w*hs[4*k+ 3];
        dd1 += a1.x*hs[4*k+ 4]+a1.y*hs[4*k+ 5]+a1.z*hs[4*k+ 6]+a1.w*hs[4*k+ 7];
        dd2 += a2.x*hs[4*k+ 8]+a2.y*hs[4*k+ 9]+a2.z*hs[4*k+10]+a2.w*hs[4*k+11];
        dd3 += a3.x*hs[4*k+12]+a3.y*hs[4*k+13]+a3.z*hs[4*k+14]+a3.w*hs[4*k+15];
      }
      float d = (dd0+dd1)+(dd2+dd3);
      float sim = (d / fmaxf(nl[b2*NN+n2]*nh2, 1e-8f)) * 0.0625f;
      S += expf(sim - 0.0625f);
    }
    for (int o=32;o;o>>=1) S += __shfl_down(S,o);
    if (lane == 0) Sres[w] = S;
    __syncthreads();
    float Stot = (Sres[0]+Sres[1])+(Sres[2]+Sres[3]);
    if (w == w2){
      // owning wave: registers (mask, pn, pv, h, nhg) still live across barriers
      float invS = 1.0f / Stot;
      float bestQ = -INFINITY; int bestN = 1<<30;
      unsigned long long mm = mask;
      while (mm){
        int src = __builtin_ctzll(mm); mm &= mm-1;
        int   n  = __shfl(pn, src);
        float gv = __shfl(pv, src);
        float4 a = ((const float4*)(LLF + ((size_t)b*NN + n)*ND))[lane];
        float d = a.x*h.x + a.y*h.y + a.z*h.z + a.w*h.w;
        for (int o=32;o;o>>=1) d += __shfl_down(d,o);
        d = __shfl(d, 0);
        float sim = (d / fmaxf(nl[b*NN+n]*nhg, 1e-8f)) * 0.0625f;
        float q = expf(sim - 0.0625f)*invS + gv;
        if (q > bestQ || (q == bestQ && n < bestN)){ bestQ = q; bestN = n; }
      }
      if (lane == 0) idx[g] = bestN;
    }
    __syncthreads();                         // Sres reuse guard for next w2
  }
}

// ---------------- last-resort fallback (tiny ws) ----------------
__launch_bounds__(256)
__global__ void kstats(const float* __restrict__ A, const float* __restrict__ Bm,
                       const float* __restrict__ nl, const float* __restrict__ nh,
                       float* __restrict__ Mout, float* __restrict__ Sinv){
  __shared__ float As[64][33];
  __shared__ float Bs[64][33];
  __shared__ float Cs[64][65];
  const int b  = blockIdx.x >> 5;
  const int m0 = (blockIdx.x & 31) << 6;
  const float* Ab = A  + (size_t)b*NN*ND;
  const float* Bb = Bm + (size_t)b*NN*ND;
  const int tid = threadIdx.x;
  const int tx = tid & 15, ty = tid >> 4;
  float nhv[4];
  #pragma unroll
  for (int j=0;j<4;j++) nhv[j] = nh[b*NN + m0 + tx*4 + j];
  float Mr = -INFINITY, Sr = 0.0f;
  for (int nt=0; nt<NN; nt+=64){
    float acc[4][4] = {{0.f,0.f,0.f,0.f},{0.f,0.f,0.f,0.f},{0.f,0.f,0.f,0.f},{0.f,0.f,0.f,0.f}};
    for (int kc=0; kc<ND; kc+=32){
      __syncthreads();
      #pragma unroll
      for (int s=0;s<2;s++){
        int f = tid + (s<<8);
        int r = f >> 3;
        int c = (f & 7) << 2;
        float4 va = *(const float4*)(Ab + (size_t)(nt+r)*ND + kc + c);
        As[r][c]=va.x; As[r][c+1]=va.y; As[r][c+2]=va.z; As[r][c+3]=va.w;
        float4 vb = *(const float4*)(Bb + (size_t)(m0+r)*ND + kc + c);
        Bs[r][c]=vb.x; Bs[r][c+1]=vb.y; Bs[r][c+2]=vb.z; Bs[r][c+3]=vb.w;
      }
      __syncthreads();
      #pragma unroll 4
      for (int k=0;k<32;k++){
        float a0=As[ty*4+0][k], a1=As[ty*4+1][k], a2=As[ty*4+2][k], a3=As[ty*4+3][k];
        float b0=Bs[tx*4+0][k], b1=Bs[tx*4+1][k], b2=Bs[tx*4+2][k], b3=Bs[tx*4+3][k];
        acc[0][0]+=a0*b0; acc[0][1]+=a0*b1; acc[0][2]+=a0*b2; acc[0][3]+=a0*b3;
        acc[1][0]+=a1*b0; acc[1][1]+=a1*b1; acc[1][2]+=a1*b2; acc[1][3]+=a1*b3;
        acc[2][0]+=a2*b0; acc[2][1]+=a2*b1; acc[2][2]+=a2*b2; acc[2][3]+=a2*b3;
        acc[3][0]+=a3*b0; acc[3][1]+=a3*b1; acc[3][2]+=a3*b2; acc[3][3]+=a3*b3;
      }
    }
    float nlv[4];
    #pragma unroll
    for (int i=0;i<4;i++) nlv[i] = nl[b*NN + nt + ty*4 + i];
    __syncthreads();
    #pragma unroll
    for (int i=0;i<4;i++)
      #pragma unroll
      for (int j=0;j<4;j++){
        float denom = fmaxf(nlv[i]*nhv[j], 1e-8f);
        Cs[ty*4+i][tx*4+j] = (acc[i][j]/denom)*0.0625f;
      }
    __syncthreads();
    if (tid < 64){
      float tmax = -INFINITY;
      #pragma unroll 8
      for (int r=0;r<64;r++) tmax = fmaxf(tmax, Cs[r][tid]);
      float newM = fmaxf(Mr, tmax);
      float s = 0.0f;
      #pragma unroll 4
      for (int r=0;r<64;r++) s += expf(Cs[r][tid]-newM);
      Sr = Sr*expf(Mr-newM) + s;
      Mr = newM;
    }
  }
  if (tid < 64){
    Mout[b*NN+m0+tid] = Mr;
    Sinv[b*NN+m0+tid] = 1.0f/Sr;
  }
}

__launch_bounds__(256)
__global__ void kargmax(const float* __restrict__ A, const float* __restrict__ Bm,
                        const float* __restrict__ nl, const float* __restrict__ nh,
                        const float* __restrict__ Mv, const float* __restrict__ Sv,
                        int* __restrict__ idxout){
  __shared__ float As[64][33];
  __shared__ float Bs[64][33];
  __shared__ float Vs[16][64];
  __shared__ int   Is[16][64];
  const int b  = blockIdx.x >> 5;
  const int m0 = (blockIdx.x & 31) << 6;
  const float* Ab = A  + (size_t)b*NN*ND;
  const float* Bb = Bm + (size_t)b*NN*ND;
  const int tid = threadIdx.x;
  const int tx = tid & 15, ty = tid >> 4;
  float nhv[4], Mj[4], iSj[4];
  #pragma unroll
  for (int j=0;j<4;j++){
    int m = m0 + tx*4 + j;
    nhv[j] = nh[b*NN + m];
    Mj[j]  = Mv[b*NN + m];
    iSj[j] = Sv[b*NN + m];
  }
  float bestV = -INFINITY; int bestN = 0;
  for (int nt=0; nt<NN; nt+=64){
    float acc[4][4] = {{0.f,0.f,0.f,0.f},{0.f,0.f,0.f,0.f},{0.f,0.f,0.f,0.f},{0.f,0.f,0.f,0.f}};
    for (int kc=0; kc<ND; kc+=32){
      __syncthreads();
      #pragma unroll
      for (int s=0;s<2;s++){
        int f = tid + (s<<8);
        int r = f >> 3;
        int c = (f & 7) << 2;
        float4 va = *(const float4*)(Ab + (size_t)(nt+r)*ND + kc + c);
        As[r][c]=va.x; As[r][c+1]=va.y; As[r][c+2]=va.z; As[r][c+3]=va.w;
        float4 vb = *(const float4*)(Bb + (size_t)(m0+r)*ND + kc + c);
        Bs[r][c]=vb.x; Bs[r][c+1]=vb.y; Bs[r][c+2]=vb.z; Bs[r][c+3]=vb.w;
      }
      __syncthreads();
      #pragma unroll 4
      for (int k=0;k<32;k++){
        float a0=As[ty*4+0][k], a1=As[ty*4+1][k], a2=As[ty*4+2][k], a3=As[ty*4+3][k];
        float b0=Bs[tx*4+0][k], b1=Bs[tx*4+1][k], b2=Bs[tx*4+2][k], b3=Bs[tx*4+3][k];
        acc[0][0]+=a0*b0; acc[0][1]+=a0*b1; acc[0][2]+=a0*b2; acc[0][3]+=a0*b3;
        acc[1][0]+=a1*b0; acc[1][1]+=a1*b1; acc[1][2]+=a1*b2; acc[1][3]+=a1*b3;
        acc[2][0]+=a2*b0; acc[2][1]+=a2*b1; acc[2][2]+=a2*b2; acc[2][3]+=a2*b3;
        acc[3][0]+=a3*b0; acc[3][1]+=a3*b1; acc[3][2]+=a3*b2; acc[3][3]+=a3*b3;
      }
    }
    float nlv[4];
    #pragma unroll
    for (int i=0;i<4;i++) nlv[i] = nl[b*NN + nt + ty*4 + i];
    float lv[4]; int li[4];
    #pragma unroll
    for (int j=0;j<4;j++){ lv[j] = -INFINITY; li[j] = 0; }
    #pragma unroll
    for (int i=0;i<4;i++){
      int n = nt + ty*4 + i;
      #pragma unroll
      for (int j=0;j<4;j++){
        float denom = fmaxf(nlv[i]*nhv[j], 1e-8f);
        float sim = (acc[i][j]/denom)*0.0625f;
        float p = expf(sim - Mj[j]) * iSj[j];
        float v = p + gumbelv((unsigned)b, (unsigned)n, (unsigned)(m0 + tx*4 + j));
        if (v > lv[j]) { lv[j] = v; li[j] = n; }
      }
    }
    __syncthreads();
    #pragma unroll
    for (int j=0;j<4;j++){ Vs[ty][tx*4+j]=lv[j]; Is[ty][tx*4+j]=li[j]; }
    __syncthreads();
    if (tid < 64){
      #pragma unroll 4
      for (int t=0;t<16;t++){
        float v = Vs[t][tid];
        if (v > bestV){ bestV = v; bestN = Is[t][tid]; }
      }
    }
  }
  if (tid < 64) idxout[b*NN + m0 + tid] = bestN;
}

// ---------------- shared tail kernels ----------------
__global__ void ksort(const int* __restrict__ idx, int* __restrict__ cntg,
                      int* __restrict__ offg, int* __restrict__ sl){
  __shared__ int c[NN];
  __shared__ int part[256];
  int b = blockIdx.x, tid = threadIdx.x;
  for (int v=tid; v<NN; v+=256) c[v]=0;
  __syncthreads();
  for (int j=tid; j<NN; j+=256) atomicAdd(&c[idx[b*NN+j]], 1);
  __syncthreads();
  int base = tid*8, s=0, lc[8];
  #pragma unroll
  for (int k=0;k<8;k++){ lc[k]=c[base+k]; s+=lc[k]; }
  part[tid]=s; __syncthreads();
  for (int o=1;o<256;o<<=1){
    int v = (tid>=o)? part[tid-o] : 0;
    __syncthreads();
    part[tid]+=v;
    __syncthreads();
  }
  int run = part[tid]-s;
  #pragma unroll
  for (int k=0;k<8;k++){
    int v = base+k;
    cntg[b*NN+v]=lc[k];
    offg[b*NN+v]=run;
    for (int j=0;j<lc[k];j++) sl[b*NN+run+j]=v;
    run += lc[k];
  }
}

__global__ void kw(const float* __restrict__ LLF, const float* __restrict__ HLF,
                   const float* __restrict__ nl, const float* __restrict__ nh,
                   const int* __restrict__ sl, float* __restrict__ w){
  int g = blockIdx.x*4 + (threadIdx.x>>6);
  int lane = threadIdx.x & 63;
  int b = g >> 11;
  int s = sl[g];
  float4 a = ((const float4*)(HLF + ((size_t)b*NN + s)*ND))[lane];
  float4 l = ((const float4*)(LLF + (size_t)g*ND))[lane];
  float d = a.x*l.x + a.y*l.y + a.z*l.z + a.w*l.w;
  for (int o=32;o;o>>=1) d += __shfl_down(d,o);
  if (lane==0){
    float denom = fmaxf(nh[b*NN+s]*nl[g], 1e-8f);
    w[g] = d/denom;
  }
}

__global__ void knoise(const float* __restrict__ w, float* __restrict__ nz){
  int b = blockIdx.x, tid = threadIdx.x;
  __shared__ float sred[4];
  float x[8]; float mx = -INFINITY;
  #pragma unroll
  for (int k=0;k<8;k++){ x[k] = w[b*NN + tid*8 + k] / 0.1f; mx = fmaxf(mx, x[k]); }
  for (int o=32;o;o>>=1) mx = fmaxf(mx, __shfl_down(mx,o));
  mx = __shfl(mx, 0);
  if ((tid&63)==0) sred[tid>>6] = mx;
  __syncthreads();
  mx = fmaxf(fmaxf(sred[0],sred[1]), fmaxf(sred[2],sred[3]));
  __syncthreads();
  float e[8]; float s = 0.f;
  #pragma unroll
  for (int k=0;k<8;k++){ e[k] = expf(x[k]-mx); s += e[k]; }
  for (int o=32;o;o>>=1) s += __shfl_down(s,o);
  s = __shfl(s, 0);
  if ((tid&63)==0) sred[tid>>6] = s;
  __syncthreads();
  s = sred[0]+sred[1]+sred[2]+sred[3];
  #pragma unroll
  for (int k=0;k<8;k++) nz[b*NN + tid*8 + k] = e[k]/s;
}

__global__ void kfinal(const float* __restrict__ LLF, const float* __restrict__ HLF,
                       const int* __restrict__ cnt, const int* __restrict__ off,
                       const float* __restrict__ nz, float* __restrict__ out){
  int row = blockIdx.x;
  int lane = threadIdx.x;
  int b = row >> 11;
  float4 h = ((const float4*)(HLF + (size_t)row*ND))[lane];
  int c = cnt[row];
  if (c > 0){
    int i = off[row] + c - 1;
    float ns = nz[b*NN + i];
    float4 l = ((const float4*)(LLF + ((size_t)(b*NN + i))*ND))[lane];
    h.x += l.x*ns; h.y += l.y*ns; h.z += l.z*ns; h.w += l.w*ns;
  }
  ((float4*)(out + (size_t)row*ND))[lane] = h;
}

extern "C" void kernel_launch(void* const* d_in, const int* in_sizes, int n_in,
                              void* d_out, int out_size, void* d_ws, size_t ws_size,
                              hipStream_t stream){
  const float* LLF = (const float*)d_in[0];
  const float* HLF = (const float*)d_in[1];
  float* out = (float*)d_out;
  float* ws = (float*)d_ws;

  float* nl  = ws;
  float* nh  = ws + 1*(size_t)BNtot;
  float* iS  = ws + 2*(size_t)BNtot;                   // last-resort tier only
  int*   idx = (int*)(ws + 3*(size_t)BNtot);
  int*   cnt = (int*)(ws + 4*(size_t)BNtot);
  int*   off = (int*)(ws + 5*(size_t)BNtot);
  int*   sl  = (int*)(ws + 6*(size_t)BNtot);
  float* wv  = ws + 7*(size_t)BNtot;
  float* nz  = ws + 8*(size_t)BNtot;
  unsigned* pck = (unsigned*)(ws + 9*(size_t)BNtot);   // 32*BNtot packed candidates (4.2 MB)
  const size_t needA = (9 + 32) * (size_t)BNtot * 4;   // ~5.4 MB

  if (ws_size >= needA){
    // [norms + full gumbel] -> interval-resolve with block-cooperative exact fallback
    hipLaunchKernelGGL(kfuse1,  dim3(2048),    dim3(256), 0, stream, LLF, HLF, nl, nh, pck);
    hipLaunchKernelGGL(kresolve,dim3(BNtot/4), dim3(256), 0, stream, LLF, HLF, nl, nh, pck, idx);
  } else {
    float* Mv = ws + 9*(size_t)BNtot;
    hipLaunchKernelGGL(knorms,   dim3(BNtot),    dim3(128), 0, stream, LLF, HLF, nl, nh);
    hipLaunchKernelGGL(kstats,   dim3(NB*32),    dim3(256), 0, stream, LLF, HLF, nl, nh, Mv, iS);
    hipLaunchKernelGGL(kargmax,  dim3(NB*32),    dim3(256), 0, stream, LLF, HLF, nl, nh, Mv, iS, idx);
  }

  hipLaunchKernelGGL(ksort,  dim3(NB),      dim3(256), 0, stream, idx, cnt, off, sl);
  hipLaunchKernelGGL(kw,     dim3(BNtot/4), dim3(256), 0, stream, LLF, HLF, nl, nh, sl, wv);
  hipLaunchKernelGGL(knoise, dim3(NB),      dim3(256), 0, stream, wv, nz);
  hipLaunchKernelGGL(kfinal, dim3(BNtot),   dim3(64),  0, stream, LLF, HLF, cnt, off, nz, out);
}